// Round 3
// baseline (618.162 us; speedup 1.0000x reference)
//
#include <hip/hip_runtime.h>
#include <stdint.h>

// ---------- types ----------
typedef __attribute__((ext_vector_type(8))) __bf16 bf16x8;
typedef __attribute__((ext_vector_type(8))) unsigned short u16x8;
typedef __attribute__((ext_vector_type(4))) float f32x4;

// ---------- workspace layout ----------
// float units:
#define WSF_M1 0        // M1n = -(fb1^T @ W1^T)  [128x128]
#define WSF_M2 16384    // M2n [64x64]
#define WSF_M3 20480    // M3n [32x32]
#define WSF_C  21504    // c1[128], c2[64], c3[32]
// frag region starts at float offset 43520/2... (ushort offset 43520 from ws base? kept as R2)
#define F_W1T 0         // 25kt x 8nt
#define F_M1N 102400    // 4 x 8
#define F_U1T 118784    // 4 x 8
#define F_W2T 135168    // 4 x 4
#define F_M2N 143360    // 2 x 4
#define F_U2T 147456    // 2 x 4
#define F_W3T 151552    // 2 x 2
#define F_M3N 153600    // 1 x 2
#define F_U3T 154624    // 1 x 2
#define F_CLF 155648    // 1 x 1

__device__ __forceinline__ unsigned short f2bf(float f) {
  uint32_t u = __builtin_bit_cast(uint32_t, f);
  u += 0x7fffu + ((u >> 16) & 1u);   // round-to-nearest-even
  return (unsigned short)(u >> 16);
}

extern "C" __device__ float __ocml_native_exp2_f32(float);
__device__ __forceinline__ float tanh_fast(float x) {
  float e = __ocml_native_exp2_f32(x * 2.8853900817779268f);
  return 1.0f - 2.0f * __builtin_amdgcn_rcpf(e + 1.0f);
}

__device__ __forceinline__ f32x4 mfma16(bf16x8 a, bf16x8 b, f32x4 c) {
  return __builtin_amdgcn_mfma_f32_16x16x32_bf16(a, b, c, 0, 0, 0);
}

__device__ __forceinline__ bf16x8 lds_frag(const unsigned short* p) {
  u16x8 v = *(const u16x8*)p;
  return __builtin_bit_cast(bf16x8, v);
}
__device__ __forceinline__ bf16x8 glb_frag(const unsigned short* __restrict__ base,
                                           int fi, int lane) {
  u16x8 v = *(const u16x8*)(base + (((size_t)fi * 64 + lane) << 3));
  return __builtin_bit_cast(bf16x8, v);
}
__device__ __forceinline__ bf16x8 pack8(f32x4 a, f32x4 b) {
  u16x8 v;
  v[0]=f2bf(a[0]); v[1]=f2bf(a[1]); v[2]=f2bf(a[2]); v[3]=f2bf(a[3]);
  v[4]=f2bf(b[0]); v[5]=f2bf(b[1]); v[6]=f2bf(b[2]); v[7]=f2bf(b[3]);
  return __builtin_bit_cast(bf16x8, v);
}

// ============ prep A: M1 via P = W1 @ fb1 (coalesced fb1 row reads) ========
__global__ __launch_bounds__(128)
void pcnet_prep_m1(const float* __restrict__ W1_w, const float* __restrict__ fb1_w,
                   float* __restrict__ wsf)
{
  const int b = blockIdx.x;      // P row (W1 out-neuron)
  const int a = threadIdx.x;     // P col (fb1 out-neuron)
  const float* __restrict__ wr = W1_w + (size_t)b*784;
  float s0=0.f, s1=0.f, s2=0.f, s3=0.f;
  for (int d = 0; d < 784; d += 4) {
    s0 += wr[d]   * fb1_w[(d  )*128 + a];
    s1 += wr[d+1] * fb1_w[(d+1)*128 + a];
    s2 += wr[d+2] * fb1_w[(d+2)*128 + a];
    s3 += wr[d+3] * fb1_w[(d+3)*128 + a];
  }
  wsf[WSF_M1 + a*128 + b] = -((s0+s1)+(s2+s3));   // M1n[a][b] = -P[b][a]
}

// ============ prep B: M2/M3/c1/c2/c3, one wave per element =================
// w: [16384,20480) M2 | [20480,21504) M3 | [21504,21632) c1 | [21632,21696) c2
//    [21696,21728) c3
__global__ __launch_bounds__(256)
void pcnet_prep_rest(
    const float* __restrict__ W1_w, const float* __restrict__ W1_b,
    const float* __restrict__ W2_w, const float* __restrict__ W2_b,
    const float* __restrict__ W3_w, const float* __restrict__ W3_b,
    const float* __restrict__ fb1_b,
    const float* __restrict__ fb2_w, const float* __restrict__ fb2_b,
    const float* __restrict__ fb3_w, const float* __restrict__ fb3_b,
    float* __restrict__ wsf)
{
  const int w    = 16384 + blockIdx.x * 4 + (threadIdx.x >> 6);
  const int lane = threadIdx.x & 63;
  float s = 0.f;
  if (w < 20480) {
    const int t = w - 16384, a = t >> 6, b = t & 63;
    for (int d = lane; d < 128; d += 64) s += fb2_w[d*64 + a] * W2_w[b*128 + d];
  } else if (w < 21504) {
    const int t = w - 20480, a = t >> 5, b = t & 31;
    s = fb3_w[lane*32 + a] * W3_w[b*64 + lane];
  } else if (w < 21632) {
    const int b = w - 21504;
    for (int d = lane; d < 784; d += 64) s += fb1_b[d] * W1_w[b*784 + d];
  } else if (w < 21696) {
    const int b = w - 21632;
    for (int d = lane; d < 128; d += 64) s += fb2_b[d] * W2_w[b*128 + d];
  } else if (w < 21728) {
    const int b = w - 21696;
    s = fb3_b[lane] * W3_w[b*64 + lane];
  }
#pragma unroll
  for (int off = 32; off >= 1; off >>= 1) s += __shfl_down(s, off, 64);
  if (lane == 0) {
    if (w < 20480)      { const int t = w - 16384; wsf[WSF_M2 + (t >> 6)*64 + (t & 63)] = -s; }
    else if (w < 21504) { const int t = w - 20480; wsf[WSF_M3 + (t >> 5)*32 + (t & 31)] = -s; }
    else if (w < 21632) { const int b = w - 21504; wsf[WSF_C + b]       = W1_b[b] - s; }
    else if (w < 21696) { const int b = w - 21632; wsf[WSF_C + 128 + b] = W2_b[b] - s; }
    else if (w < 21728) { const int b = w - 21696; wsf[WSF_C + 192 + b] = W3_b[b] - s; }
  }
}

// ============ prep C: swizzle all B-operands into MFMA fragment order ======
__device__ __forceinline__ void swz_T(const float* __restrict__ src, int ld, int Kv, int Nv,
                                      int NT, unsigned short* __restrict__ dst, int f, int lane) {
  const int kt = f / NT, nt = f - kt*NT;
  const int m = lane & 15, q = lane >> 4;
  const int n = nt*16 + m;
  u16x8 v;
#pragma unroll
  for (int j = 0; j < 8; ++j) {
    const int k = kt*32 + q*8 + j;
    float val = (k < Kv && n < Nv) ? src[(size_t)n*ld + k] : 0.f;  // B[k][n] = W[n][k]
    v[j] = f2bf(val);
  }
  *(u16x8*)(dst + (((size_t)f*64 + lane) << 3)) = v;
}
__device__ __forceinline__ void swz_R(const float* __restrict__ src, int N, int NT,
                                      unsigned short* __restrict__ dst, int f, int lane) {
  const int kt = f / NT, nt = f - kt*NT;
  const int m = lane & 15, q = lane >> 4;
  const int n = nt*16 + m;
  u16x8 v;
#pragma unroll
  for (int j = 0; j < 8; ++j) {
    const int k = kt*32 + q*8 + j;
    v[j] = f2bf(src[k*N + n]);          // row-major [K][N]
  }
  *(u16x8*)(dst + (((size_t)f*64 + lane) << 3)) = v;
}

__global__ void pcnet_swz(
    const float* __restrict__ W1_w, const float* __restrict__ U1_w,
    const float* __restrict__ W2_w, const float* __restrict__ U2_w,
    const float* __restrict__ W3_w, const float* __restrict__ U3_w,
    const float* __restrict__ clf_w, const float* __restrict__ wsf,
    unsigned short* __restrict__ frags)
{
  const int t = blockIdx.x*256 + threadIdx.x;
  if (t >= 305*64) return;
  const int fg = t >> 6, lane = t & 63;
  if      (fg < 200) swz_T(W1_w, 784, 784, 128, 8, frags + F_W1T, fg,       lane);
  else if (fg < 232) swz_R(wsf + WSF_M1, 128, 8,  frags + F_M1N, fg - 200, lane);
  else if (fg < 264) swz_T(U1_w, 128, 128, 128, 8, frags + F_U1T, fg - 232, lane);
  else if (fg < 280) swz_T(W2_w, 128, 128, 64, 4, frags + F_W2T, fg - 264, lane);
  else if (fg < 288) swz_R(wsf + WSF_M2, 64, 4,   frags + F_M2N, fg - 280, lane);
  else if (fg < 296) swz_T(U2_w, 64, 64, 64, 4,   frags + F_U2T, fg - 288, lane);
  else if (fg < 300) swz_T(W3_w, 64, 64, 32, 2,   frags + F_W3T, fg - 296, lane);
  else if (fg < 302) swz_R(wsf + WSF_M3, 32, 2,   frags + F_M3N, fg - 300, lane);
  else if (fg < 304) swz_T(U3_w, 32, 32, 32, 2,   frags + F_U3T, fg - 302, lane);
  else               swz_T(clf_w, 32, 32, 10, 1,  frags + F_CLF, fg - 304, lane);
}

// ============ main fused kernel: 32 rows/WG, 4 waves col-sliced =============
// Sequential accumulator passes keep peak VGPR demand ~90-110 -> no spill at
// the (256,3) cap of 168. Phase 1 loads A-frags straight from global x
// (no LDS staging, no barriers).
__global__ __launch_bounds__(256, 3)
void pcnet_main(
    const float* __restrict__ x,
    const float* __restrict__ cvec,   // c1[128] c2[64] c3[32]
    const float* __restrict__ U1_b, const float* __restrict__ U2_b,
    const float* __restrict__ U3_b, const float* __restrict__ clf_b,
    const unsigned short* __restrict__ frags,
    const int* __restrict__ steps_p,
    float* __restrict__ out)
{
  const int tid  = threadIdx.x;
  const int wave = tid >> 6;
  const int lane = tid & 63;
  const int q = lane >> 4;
  const int m = lane & 15;
  const int rowBase = blockIdx.x << 5;     // 32 rows per WG

  __shared__ unsigned short h1b[32*136];
  __shared__ unsigned short h2b[32*72];
  __shared__ unsigned short h3b[32*40];

  const unsigned short* fW1T = frags + F_W1T;
  const unsigned short* fM1N = frags + F_M1N;
  const unsigned short* fU1T = frags + F_U1T;
  const unsigned short* fW2T = frags + F_W2T;
  const unsigned short* fM2N = frags + F_M2N;
  const unsigned short* fU2T = frags + F_U2T;
  const unsigned short* fW3T = frags + F_W3T;
  const unsigned short* fM3N = frags + F_M3N;
  const unsigned short* fU3T = frags + F_U3T;
  const unsigned short* fCLF = frags + F_CLF;

  // zero h LDS early (visible after the one pre-loop barrier)
  {
    uint32_t* p = (uint32_t*)h1b;
    for (int i = tid; i < 2176; i += 256) p[i] = 0u;
    p = (uint32_t*)h2b;
    for (int i = tid; i < 1152; i += 256) p[i] = 0u;
    p = (uint32_t*)h3b;
    for (int i = tid; i < 640; i += 256) p[i] = 0u;
  }

  // ---------------- phase 1: A1 = x @ W1^T + c1 (registers, C-layout)
  f32x4 A1[2][2];
#pragma unroll
  for (int nt = 0; nt < 2; ++nt) {
    const float cv = cvec[(2*wave + nt)*16 + m];
    const f32x4 v = {cv, cv, cv, cv};
    A1[0][nt] = v; A1[1][nt] = v;
  }

  // A-frag rows owned by this lane: m (a0) and m+16 (a1); k-slice q*8..q*8+7
  const float* __restrict__ xr0 = x + (size_t)(rowBase + m)*784      + q*8;
  const float* __restrict__ xr1 = x + (size_t)(rowBase + 16 + m)*784 + q*8;

#pragma unroll 4
  for (int kt = 0; kt < 24; ++kt) {
    const f32x4 p0 = *(const f32x4*)(xr0 + kt*32);
    const f32x4 p1 = *(const f32x4*)(xr0 + kt*32 + 4);
    const f32x4 p2 = *(const f32x4*)(xr1 + kt*32);
    const f32x4 p3 = *(const f32x4*)(xr1 + kt*32 + 4);
    const bf16x8 a0 = pack8(p0, p1);
    const bf16x8 a1 = pack8(p2, p3);
#pragma unroll
    for (int nt = 0; nt < 2; ++nt) {
      const bf16x8 b = glb_frag(fW1T, kt*8 + 2*wave + nt, lane);
      A1[0][nt] = mfma16(a0, b, A1[0][nt]);
      A1[1][nt] = mfma16(a1, b, A1[1][nt]);
    }
  }
  { // kt == 24: k = 768 + q*8 + j, valid only for q < 2 (784 = 24.5*32);
    // B-frags are zero-padded beyond k=783, but mask loads to stay in-bounds.
    f32x4 p0 = {0,0,0,0}, p1 = p0, p2 = p0, p3 = p0;
    if (q < 2) {
      p0 = *(const f32x4*)(xr0 + 768);
      p1 = *(const f32x4*)(xr0 + 772);
      p2 = *(const f32x4*)(xr1 + 768);
      p3 = *(const f32x4*)(xr1 + 772);
    }
    const bf16x8 a0 = pack8(p0, p1);
    const bf16x8 a1 = pack8(p2, p3);
#pragma unroll
    for (int nt = 0; nt < 2; ++nt) {
      const bf16x8 b = glb_frag(fW1T, 24*8 + 2*wave + nt, lane);
      A1[0][nt] = mfma16(a0, b, A1[0][nt]);
      A1[1][nt] = mfma16(a1, b, A1[1][nt]);
    }
  }

  // ---------------- masters (fp32 regs)
  f32x4 h1v[2][2], h2v[2], h3v;
  {
    const f32x4 z = {0.f,0.f,0.f,0.f};
#pragma unroll
    for (int rt = 0; rt < 2; ++rt) { h1v[rt][0] = z; h1v[rt][1] = z; h2v[rt] = z; }
    h3v = z;
  }

  const int nt3 = wave >> 1;            // h3 col tile owned by this wave
  const int rt3 = wave & 1;             // h3 row tile owned by this wave
  const float c3v  = cvec[192 + nt3*16 + m];
  const float b3v  = U3_b[nt3*16 + m];
  const float c2v  = cvec[128 + wave*16 + m];
  const float b2v  = U2_b[wave*16 + m];
  const float b1v0 = U1_b[(2*wave + 0)*16 + m];
  const float b1v1 = U1_b[(2*wave + 1)*16 + m];

  __syncthreads();

  // ---------------- 5-step recurrence
  const int S = *steps_p;
  for (int s = 0; s < S; ++s) {
    // old-h fragments
    bf16x8 h2f[2][2];
#pragma unroll
    for (int kt = 0; kt < 2; ++kt)
#pragma unroll
      for (int rt = 0; rt < 2; ++rt)
        h2f[kt][rt] = lds_frag(h2b + (rt*16 + m)*72 + kt*32 + q*8);
    const bf16x8 h3f = lds_frag(h3b + (rt3*16 + m)*40 + q*8);
    bf16x8 h2s[2];
#pragma unroll
    for (int kt = 0; kt < 2; ++kt) h2s[kt] = (wave & 1) ? h2f[kt][1] : h2f[kt][0];

    // ---- level 3
    {
      f32x4 z3a = {c3v,c3v,c3v,c3v};
      f32x4 z3b = {b3v,b3v,b3v,b3v};
#pragma unroll
      for (int kt = 0; kt < 2; ++kt) {
        const bf16x8 b = glb_frag(fW3T, kt*2 + nt3, lane);
        z3a = mfma16(h2s[kt], b, z3a);
      }
      { const bf16x8 b = glb_frag(fM3N, nt3, lane); z3a = mfma16(h3f, b, z3a); }
      { const bf16x8 b = glb_frag(fU3T, nt3, lane); z3b = mfma16(h3f, b, z3b); }
#pragma unroll
      for (int r = 0; r < 4; ++r)
        h3v[r] += tanh_fast(z3a[r]) + tanh_fast(z3b[r]);
    }

    // ---- level 2: U2 part (h2-sourced), retire immediately
    {
      f32x4 z2b[2];
      { const f32x4 v = {b2v,b2v,b2v,b2v}; z2b[0]=v; z2b[1]=v; }
#pragma unroll
      for (int kt = 0; kt < 2; ++kt) {
        const bf16x8 b = glb_frag(fU2T, kt*4 + wave, lane);
#pragma unroll
        for (int rt = 0; rt < 2; ++rt) z2b[rt] = mfma16(h2f[kt][rt], b, z2b[rt]);
      }
#pragma unroll
      for (int rt = 0; rt < 2; ++rt)
#pragma unroll
        for (int r = 0; r < 4; ++r) h2v[rt][r] += tanh_fast(z2b[rt][r]);
    }

    // ---- level 2: M2 partial + W2 pass over h1, then retire
    {
      f32x4 z2a[2];
      { const f32x4 v = {c2v,c2v,c2v,c2v}; z2a[0]=v; z2a[1]=v; }
#pragma unroll
      for (int kt = 0; kt < 2; ++kt) {
        const bf16x8 b = glb_frag(fM2N, kt*4 + wave, lane);
#pragma unroll
        for (int rt = 0; rt < 2; ++rt) z2a[rt] = mfma16(h2f[kt][rt], b, z2a[rt]);
      }
#pragma unroll
      for (int kt = 0; kt < 4; ++kt) {
        const bf16x8 a0 = lds_frag(h1b + (0*16 + m)*136 + kt*32 + q*8);
        const bf16x8 a1 = lds_frag(h1b + (1*16 + m)*136 + kt*32 + q*8);
        const bf16x8 b  = glb_frag(fW2T, kt*4 + wave, lane);
        z2a[0] = mfma16(a0, b, z2a[0]);
        z2a[1] = mfma16(a1, b, z2a[1]);
      }
#pragma unroll
      for (int rt = 0; rt < 2; ++rt)
#pragma unroll
        for (int r = 0; r < 4; ++r) h2v[rt][r] += tanh_fast(z2a[rt][r]);
    }

    // ---- level 1: M1 pass (z1 = A1 - h1@M1), retire
    {
      f32x4 z1[2][2];
#pragma unroll
      for (int rt = 0; rt < 2; ++rt) { z1[rt][0] = A1[rt][0]; z1[rt][1] = A1[rt][1]; }
#pragma unroll
      for (int kt = 0; kt < 4; ++kt) {
        const bf16x8 a0 = lds_frag(h1b + (0*16 + m)*136 + kt*32 + q*8);
        const bf16x8 a1 = lds_frag(h1b + (1*16 + m)*136 + kt*32 + q*8);
        const bf16x8 b0 = glb_frag(fM1N, kt*8 + 2*wave + 0, lane);
        const bf16x8 b1 = glb_frag(fM1N, kt*8 + 2*wave + 1, lane);
        z1[0][0] = mfma16(a0, b0, z1[0][0]); z1[0][1] = mfma16(a0, b1, z1[0][1]);
        z1[1][0] = mfma16(a1, b0, z1[1][0]); z1[1][1] = mfma16(a1, b1, z1[1][1]);
      }
#pragma unroll
      for (int rt = 0; rt < 2; ++rt)
#pragma unroll
        for (int nt = 0; nt < 2; ++nt)
#pragma unroll
          for (int r = 0; r < 4; ++r) h1v[rt][nt][r] += tanh_fast(z1[rt][nt][r]);
    }

    // ---- level 1: U1 pass (z1 = h1@U1 + U1_b), retire
    {
      f32x4 z1[2][2];
      { const f32x4 v0 = {b1v0,b1v0,b1v0,b1v0};
        const f32x4 v1 = {b1v1,b1v1,b1v1,b1v1};
#pragma unroll
        for (int rt = 0; rt < 2; ++rt) { z1[rt][0] = v0; z1[rt][1] = v1; }
      }
#pragma unroll
      for (int kt = 0; kt < 4; ++kt) {
        const bf16x8 a0 = lds_frag(h1b + (0*16 + m)*136 + kt*32 + q*8);
        const bf16x8 a1 = lds_frag(h1b + (1*16 + m)*136 + kt*32 + q*8);
        const bf16x8 b0 = glb_frag(fU1T, kt*8 + 2*wave + 0, lane);
        const bf16x8 b1 = glb_frag(fU1T, kt*8 + 2*wave + 1, lane);
        z1[0][0] = mfma16(a0, b0, z1[0][0]); z1[0][1] = mfma16(a0, b1, z1[0][1]);
        z1[1][0] = mfma16(a1, b0, z1[1][0]); z1[1][1] = mfma16(a1, b1, z1[1][1]);
      }
#pragma unroll
      for (int rt = 0; rt < 2; ++rt)
#pragma unroll
        for (int nt = 0; nt < 2; ++nt)
#pragma unroll
          for (int r = 0; r < 4; ++r) h1v[rt][nt][r] += tanh_fast(z1[rt][nt][r]);
    }

    __syncthreads();   // everyone done reading old h
    // write back new h (bf16, C-layout: row = rt*16 + q*4 + r, cols owned by wave)
#pragma unroll
    for (int rt = 0; rt < 2; ++rt) {
#pragma unroll
      for (int nt = 0; nt < 2; ++nt)
#pragma unroll
        for (int r = 0; r < 4; ++r)
          h1b[(rt*16 + q*4 + r)*136 + (2*wave + nt)*16 + m] = f2bf(h1v[rt][nt][r]);
#pragma unroll
      for (int r = 0; r < 4; ++r)
        h2b[(rt*16 + q*4 + r)*72 + wave*16 + m] = f2bf(h2v[rt][r]);
    }
#pragma unroll
    for (int r = 0; r < 4; ++r)
      h3b[(rt3*16 + q*4 + r)*40 + nt3*16 + m] = f2bf(h3v[r]);
    __syncthreads();
  }

  // ---------------- epilogue: out = h3 @ clf^T + clf_b (waves 0,1 = row tiles)
  if (wave < 2) {
    f32x4 o;
    { const float cb = (m < 10) ? clf_b[m] : 0.f; o = (f32x4){cb, cb, cb, cb}; }
    const bf16x8 a = lds_frag(h3b + (wave*16 + m)*40 + q*8);
    const bf16x8 b = glb_frag(fCLF, 0, lane);
    o = mfma16(a, b, o);
    if (m < 10) {
#pragma unroll
      for (int r = 0; r < 4; ++r) {
        const int row = rowBase + wave*16 + q*4 + r;
        out[(size_t)row*10 + m] = o[r];
      }
    }
  }
}

// ============ launch ============
extern "C" void kernel_launch(void* const* d_in, const int* in_sizes, int n_in,
                              void* d_out, int out_size, void* d_ws, size_t ws_size,
                              hipStream_t stream)
{
  (void)in_sizes; (void)n_in; (void)out_size; (void)ws_size;
  const float* x     = (const float*)d_in[0];
  const float* W1_w  = (const float*)d_in[1];
  const float* W1_b  = (const float*)d_in[2];
  const float* U1_w  = (const float*)d_in[3];
  const float* U1_b  = (const float*)d_in[4];
  const float* W2_w  = (const float*)d_in[5];
  const float* W2_b  = (const float*)d_in[6];
  const float* U2_w  = (const float*)d_in[7];
  const float* U2_b  = (const float*)d_in[8];
  const float* W3_w  = (const float*)d_in[9];
  const float* W3_b  = (const float*)d_in[10];
  const float* U3_w  = (const float*)d_in[11];
  const float* U3_b  = (const float*)d_in[12];
  const float* fb3_w = (const float*)d_in[13];
  const float* fb3_b = (const float*)d_in[14];
  const float* fb2_w = (const float*)d_in[15];
  const float* fb2_b = (const float*)d_in[16];
  const float* fb1_w = (const float*)d_in[17];
  const float* fb1_b = (const float*)d_in[18];
  const float* clf_w = (const float*)d_in[19];
  const float* clf_b = (const float*)d_in[20];
  const int*   steps = (const int*)d_in[21];

  float* wsf = (float*)d_ws;
  unsigned short* frags = (unsigned short*)d_ws + 43520;

  hipLaunchKernelGGL(pcnet_prep_m1, dim3(128), dim3(128), 0, stream,
                     W1_w, fb1_w, wsf);
  hipLaunchKernelGGL(pcnet_prep_rest, dim3(1336), dim3(256), 0, stream,
                     W1_w, W1_b, W2_w, W2_b, W3_w, W3_b,
                     fb1_b, fb2_w, fb2_b, fb3_w, fb3_b, wsf);
  hipLaunchKernelGGL(pcnet_swz, dim3(77), dim3(256), 0, stream,
                     W1_w, U1_w, W2_w, U2_w, W3_w, U3_w, clf_w, wsf, frags);
  hipLaunchKernelGGL(pcnet_main, dim3(2048), dim3(256), 0, stream,
                     x, wsf + WSF_C, U1_b, U2_b, U3_b, clf_b, frags, steps,
                     (float*)d_out);
}

// Round 4
// 442.020 us; speedup vs baseline: 1.3985x; 1.3985x over previous
//
#include <hip/hip_runtime.h>
#include <stdint.h>

// ---------- types ----------
typedef __attribute__((ext_vector_type(8))) __bf16 bf16x8;
typedef __attribute__((ext_vector_type(8))) unsigned short u16x8;
typedef __attribute__((ext_vector_type(4))) float f32x4;

// ---------- workspace layout ----------
// float units:
#define WSF_M1 0        // M1n = -(fb1^T @ W1^T)  [128x128]
#define WSF_M2 16384    // M2n [64x64]
#define WSF_M3 20480    // M3n [32x32]
#define WSF_C  21504    // c1[128], c2[64], c3[32]
// frag region: ushort offset 43520 floats from ws base (see kernel_launch)
#define F_W1T 0         // 25kt x 8nt
#define F_M1N 102400    // 4 x 8
#define F_U1T 118784    // 4 x 8
#define F_W2T 135168    // 4 x 4
#define F_M2N 143360    // 2 x 4
#define F_U2T 147456    // 2 x 4
#define F_W3T 151552    // 2 x 2
#define F_M3N 153600    // 1 x 2
#define F_U3T 154624    // 1 x 2
#define F_CLF 155648    // 1 x 1

__device__ __forceinline__ unsigned short f2bf(float f) {
  uint32_t u = __builtin_bit_cast(uint32_t, f);
  u += 0x7fffu + ((u >> 16) & 1u);   // round-to-nearest-even
  return (unsigned short)(u >> 16);
}

extern "C" __device__ float __ocml_native_exp2_f32(float);
__device__ __forceinline__ float tanh_fast(float x) {
  float e = __ocml_native_exp2_f32(x * 2.8853900817779268f);
  return 1.0f - 2.0f * __builtin_amdgcn_rcpf(e + 1.0f);
}

__device__ __forceinline__ f32x4 mfma16(bf16x8 a, bf16x8 b, f32x4 c) {
  return __builtin_amdgcn_mfma_f32_16x16x32_bf16(a, b, c, 0, 0, 0);
}

__device__ __forceinline__ bf16x8 lds_frag(const unsigned short* p) {
  u16x8 v = *(const u16x8*)p;
  return __builtin_bit_cast(bf16x8, v);
}
__device__ __forceinline__ bf16x8 glb_frag(const unsigned short* __restrict__ base,
                                           int fi, int lane) {
  u16x8 v = *(const u16x8*)(base + (((size_t)fi * 64 + lane) << 3));
  return __builtin_bit_cast(bf16x8, v);
}
__device__ __forceinline__ bf16x8 pack8(f32x4 a, f32x4 b) {
  u16x8 v;
  v[0]=f2bf(a[0]); v[1]=f2bf(a[1]); v[2]=f2bf(a[2]); v[3]=f2bf(a[3]);
  v[4]=f2bf(b[0]); v[5]=f2bf(b[1]); v[6]=f2bf(b[2]); v[7]=f2bf(b[3]);
  return __builtin_bit_cast(bf16x8, v);
}

// ============ prep A: M1 via P = W1 @ fb1 (coalesced fb1 row reads) ========
__global__ __launch_bounds__(128)
void pcnet_prep_m1(const float* __restrict__ W1_w, const float* __restrict__ fb1_w,
                   float* __restrict__ wsf)
{
  const int b = blockIdx.x;      // P row (W1 out-neuron)
  const int a = threadIdx.x;     // P col (fb1 out-neuron)
  const float* __restrict__ wr = W1_w + (size_t)b*784;
  float s0=0.f, s1=0.f, s2=0.f, s3=0.f;
  for (int d = 0; d < 784; d += 4) {
    s0 += wr[d]   * fb1_w[(d  )*128 + a];
    s1 += wr[d+1] * fb1_w[(d+1)*128 + a];
    s2 += wr[d+2] * fb1_w[(d+2)*128 + a];
    s3 += wr[d+3] * fb1_w[(d+3)*128 + a];
  }
  wsf[WSF_M1 + a*128 + b] = -((s0+s1)+(s2+s3));   // M1n[a][b] = -P[b][a]
}

// ============ prep B: M2/M3/c1/c2/c3, one wave per element =================
__global__ __launch_bounds__(256)
void pcnet_prep_rest(
    const float* __restrict__ W1_w, const float* __restrict__ W1_b,
    const float* __restrict__ W2_w, const float* __restrict__ W2_b,
    const float* __restrict__ W3_w, const float* __restrict__ W3_b,
    const float* __restrict__ fb1_b,
    const float* __restrict__ fb2_w, const float* __restrict__ fb2_b,
    const float* __restrict__ fb3_w, const float* __restrict__ fb3_b,
    float* __restrict__ wsf)
{
  const int w    = 16384 + blockIdx.x * 4 + (threadIdx.x >> 6);
  const int lane = threadIdx.x & 63;
  float s = 0.f;
  if (w < 20480) {
    const int t = w - 16384, a = t >> 6, b = t & 63;
    for (int d = lane; d < 128; d += 64) s += fb2_w[d*64 + a] * W2_w[b*128 + d];
  } else if (w < 21504) {
    const int t = w - 20480, a = t >> 5, b = t & 31;
    s = fb3_w[lane*32 + a] * W3_w[b*64 + lane];
  } else if (w < 21632) {
    const int b = w - 21504;
    for (int d = lane; d < 784; d += 64) s += fb1_b[d] * W1_w[b*784 + d];
  } else if (w < 21696) {
    const int b = w - 21632;
    for (int d = lane; d < 128; d += 64) s += fb2_b[d] * W2_w[b*128 + d];
  } else if (w < 21728) {
    const int b = w - 21696;
    s = fb3_b[lane] * W3_w[b*64 + lane];
  }
#pragma unroll
  for (int off = 32; off >= 1; off >>= 1) s += __shfl_down(s, off, 64);
  if (lane == 0) {
    if (w < 20480)      { const int t = w - 16384; wsf[WSF_M2 + (t >> 6)*64 + (t & 63)] = -s; }
    else if (w < 21504) { const int t = w - 20480; wsf[WSF_M3 + (t >> 5)*32 + (t & 31)] = -s; }
    else if (w < 21632) { const int b = w - 21504; wsf[WSF_C + b]       = W1_b[b] - s; }
    else if (w < 21696) { const int b = w - 21632; wsf[WSF_C + 128 + b] = W2_b[b] - s; }
    else if (w < 21728) { const int b = w - 21696; wsf[WSF_C + 192 + b] = W3_b[b] - s; }
  }
}

// ============ prep C: swizzle all B-operands into MFMA fragment order ======
__device__ __forceinline__ void swz_T(const float* __restrict__ src, int ld, int Kv, int Nv,
                                      int NT, unsigned short* __restrict__ dst, int f, int lane) {
  const int kt = f / NT, nt = f - kt*NT;
  const int m = lane & 15, q = lane >> 4;
  const int n = nt*16 + m;
  u16x8 v;
#pragma unroll
  for (int j = 0; j < 8; ++j) {
    const int k = kt*32 + q*8 + j;
    float val = (k < Kv && n < Nv) ? src[(size_t)n*ld + k] : 0.f;  // B[k][n] = W[n][k]
    v[j] = f2bf(val);
  }
  *(u16x8*)(dst + (((size_t)f*64 + lane) << 3)) = v;
}
__device__ __forceinline__ void swz_R(const float* __restrict__ src, int N, int NT,
                                      unsigned short* __restrict__ dst, int f, int lane) {
  const int kt = f / NT, nt = f - kt*NT;
  const int m = lane & 15, q = lane >> 4;
  const int n = nt*16 + m;
  u16x8 v;
#pragma unroll
  for (int j = 0; j < 8; ++j) {
    const int k = kt*32 + q*8 + j;
    v[j] = f2bf(src[k*N + n]);          // row-major [K][N]
  }
  *(u16x8*)(dst + (((size_t)f*64 + lane) << 3)) = v;
}

__global__ void pcnet_swz(
    const float* __restrict__ W1_w, const float* __restrict__ U1_w,
    const float* __restrict__ W2_w, const float* __restrict__ U2_w,
    const float* __restrict__ W3_w, const float* __restrict__ U3_w,
    const float* __restrict__ clf_w, const float* __restrict__ wsf,
    unsigned short* __restrict__ frags)
{
  const int t = blockIdx.x*256 + threadIdx.x;
  if (t >= 305*64) return;
  const int fg = t >> 6, lane = t & 63;
  if      (fg < 200) swz_T(W1_w, 784, 784, 128, 8, frags + F_W1T, fg,       lane);
  else if (fg < 232) swz_R(wsf + WSF_M1, 128, 8,  frags + F_M1N, fg - 200, lane);
  else if (fg < 264) swz_T(U1_w, 128, 128, 128, 8, frags + F_U1T, fg - 232, lane);
  else if (fg < 280) swz_T(W2_w, 128, 128, 64, 4, frags + F_W2T, fg - 264, lane);
  else if (fg < 288) swz_R(wsf + WSF_M2, 64, 4,   frags + F_M2N, fg - 280, lane);
  else if (fg < 296) swz_T(U2_w, 64, 64, 64, 4,   frags + F_U2T, fg - 288, lane);
  else if (fg < 300) swz_T(W3_w, 64, 64, 32, 2,   frags + F_W3T, fg - 296, lane);
  else if (fg < 302) swz_R(wsf + WSF_M3, 32, 2,   frags + F_M3N, fg - 300, lane);
  else if (fg < 304) swz_T(U3_w, 32, 32, 32, 2,   frags + F_U3T, fg - 302, lane);
  else               swz_T(clf_w, 32, 32, 10, 1,  frags + F_CLF, fg - 304, lane);
}

// ============ main fused kernel: 32 rows/WG, 4 waves col-sliced =============
// R4 change vs R3: __launch_bounds__(256,2). R3's (256,3) capped unified
// VGPR+AGPR at ~168/wave; scheduler lookahead pushed demand past it ->
// 350 MB scratch round-trip (WRITE_SIZE 368 MB). (256,2) gives a 256-reg
// budget; sequential passes fit with headroom. 2nd arg is only a MINIMUM --
// compiler can still deliver >2 waves/EU if usage comes in low.
__global__ __launch_bounds__(256, 2)
void pcnet_main(
    const float* __restrict__ x,
    const float* __restrict__ cvec,   // c1[128] c2[64] c3[32]
    const float* __restrict__ U1_b, const float* __restrict__ U2_b,
    const float* __restrict__ U3_b, const float* __restrict__ clf_b,
    const unsigned short* __restrict__ frags,
    const int* __restrict__ steps_p,
    float* __restrict__ out)
{
  const int tid  = threadIdx.x;
  const int wave = tid >> 6;
  const int lane = tid & 63;
  const int q = lane >> 4;
  const int m = lane & 15;
  const int rowBase = blockIdx.x << 5;     // 32 rows per WG

  __shared__ unsigned short h1b[32*136];
  __shared__ unsigned short h2b[32*72];
  __shared__ unsigned short h3b[32*40];

  const unsigned short* fW1T = frags + F_W1T;
  const unsigned short* fM1N = frags + F_M1N;
  const unsigned short* fU1T = frags + F_U1T;
  const unsigned short* fW2T = frags + F_W2T;
  const unsigned short* fM2N = frags + F_M2N;
  const unsigned short* fU2T = frags + F_U2T;
  const unsigned short* fW3T = frags + F_W3T;
  const unsigned short* fM3N = frags + F_M3N;
  const unsigned short* fU3T = frags + F_U3T;
  const unsigned short* fCLF = frags + F_CLF;

  // zero h LDS early (visible after the one pre-loop barrier)
  {
    uint32_t* p = (uint32_t*)h1b;
    for (int i = tid; i < 2176; i += 256) p[i] = 0u;
    p = (uint32_t*)h2b;
    for (int i = tid; i < 1152; i += 256) p[i] = 0u;
    p = (uint32_t*)h3b;
    for (int i = tid; i < 640; i += 256) p[i] = 0u;
  }

  // ---------------- phase 1: A1 = x @ W1^T + c1 (registers, C-layout)
  f32x4 A1[2][2];
#pragma unroll
  for (int nt = 0; nt < 2; ++nt) {
    const float cv = cvec[(2*wave + nt)*16 + m];
    const f32x4 v = {cv, cv, cv, cv};
    A1[0][nt] = v; A1[1][nt] = v;
  }

  // A-frag rows owned by this lane: m (a0) and m+16 (a1); k-slice q*8..q*8+7
  const float* __restrict__ xr0 = x + (size_t)(rowBase + m)*784      + q*8;
  const float* __restrict__ xr1 = x + (size_t)(rowBase + 16 + m)*784 + q*8;

#pragma unroll 4
  for (int kt = 0; kt < 24; ++kt) {
    const f32x4 p0 = *(const f32x4*)(xr0 + kt*32);
    const f32x4 p1 = *(const f32x4*)(xr0 + kt*32 + 4);
    const f32x4 p2 = *(const f32x4*)(xr1 + kt*32);
    const f32x4 p3 = *(const f32x4*)(xr1 + kt*32 + 4);
    const bf16x8 a0 = pack8(p0, p1);
    const bf16x8 a1 = pack8(p2, p3);
#pragma unroll
    for (int nt = 0; nt < 2; ++nt) {
      const bf16x8 b = glb_frag(fW1T, kt*8 + 2*wave + nt, lane);
      A1[0][nt] = mfma16(a0, b, A1[0][nt]);
      A1[1][nt] = mfma16(a1, b, A1[1][nt]);
    }
  }
  { // kt == 24: k = 768 + q*8 + j, valid only for q < 2 (784 = 24.5*32);
    f32x4 p0 = {0,0,0,0}, p1 = p0, p2 = p0, p3 = p0;
    if (q < 2) {
      p0 = *(const f32x4*)(xr0 + 768);
      p1 = *(const f32x4*)(xr0 + 772);
      p2 = *(const f32x4*)(xr1 + 768);
      p3 = *(const f32x4*)(xr1 + 772);
    }
    const bf16x8 a0 = pack8(p0, p1);
    const bf16x8 a1 = pack8(p2, p3);
#pragma unroll
    for (int nt = 0; nt < 2; ++nt) {
      const bf16x8 b = glb_frag(fW1T, 24*8 + 2*wave + nt, lane);
      A1[0][nt] = mfma16(a0, b, A1[0][nt]);
      A1[1][nt] = mfma16(a1, b, A1[1][nt]);
    }
  }

  // ---------------- masters (fp32 regs)
  f32x4 h1v[2][2], h2v[2], h3v;
  {
    const f32x4 z = {0.f,0.f,0.f,0.f};
#pragma unroll
    for (int rt = 0; rt < 2; ++rt) { h1v[rt][0] = z; h1v[rt][1] = z; h2v[rt] = z; }
    h3v = z;
  }

  const int nt3 = wave >> 1;            // h3 col tile owned by this wave
  const int rt3 = wave & 1;             // h3 row tile owned by this wave
  const float c3v  = cvec[192 + nt3*16 + m];
  const float b3v  = U3_b[nt3*16 + m];
  const float c2v  = cvec[128 + wave*16 + m];
  const float b2v  = U2_b[wave*16 + m];
  const float b1v0 = U1_b[(2*wave + 0)*16 + m];
  const float b1v1 = U1_b[(2*wave + 1)*16 + m];

  __syncthreads();

  // ---------------- 5-step recurrence
  const int S = *steps_p;
  for (int s = 0; s < S; ++s) {
    // old-h fragments
    bf16x8 h2f[2][2];
#pragma unroll
    for (int kt = 0; kt < 2; ++kt)
#pragma unroll
      for (int rt = 0; rt < 2; ++rt)
        h2f[kt][rt] = lds_frag(h2b + (rt*16 + m)*72 + kt*32 + q*8);
    const bf16x8 h3f = lds_frag(h3b + (rt3*16 + m)*40 + q*8);
    bf16x8 h2s[2];
#pragma unroll
    for (int kt = 0; kt < 2; ++kt) h2s[kt] = (wave & 1) ? h2f[kt][1] : h2f[kt][0];

    // ---- level 3
    {
      f32x4 z3a = {c3v,c3v,c3v,c3v};
      f32x4 z3b = {b3v,b3v,b3v,b3v};
#pragma unroll
      for (int kt = 0; kt < 2; ++kt) {
        const bf16x8 b = glb_frag(fW3T, kt*2 + nt3, lane);
        z3a = mfma16(h2s[kt], b, z3a);
      }
      { const bf16x8 b = glb_frag(fM3N, nt3, lane); z3a = mfma16(h3f, b, z3a); }
      { const bf16x8 b = glb_frag(fU3T, nt3, lane); z3b = mfma16(h3f, b, z3b); }
#pragma unroll
      for (int r = 0; r < 4; ++r)
        h3v[r] += tanh_fast(z3a[r]) + tanh_fast(z3b[r]);
    }

    // ---- level 2: U2 part (h2-sourced), retire immediately
    {
      f32x4 z2b[2];
      { const f32x4 v = {b2v,b2v,b2v,b2v}; z2b[0]=v; z2b[1]=v; }
#pragma unroll
      for (int kt = 0; kt < 2; ++kt) {
        const bf16x8 b = glb_frag(fU2T, kt*4 + wave, lane);
#pragma unroll
        for (int rt = 0; rt < 2; ++rt) z2b[rt] = mfma16(h2f[kt][rt], b, z2b[rt]);
      }
#pragma unroll
      for (int rt = 0; rt < 2; ++rt)
#pragma unroll
        for (int r = 0; r < 4; ++r) h2v[rt][r] += tanh_fast(z2b[rt][r]);
    }

    // ---- level 2: M2 partial + W2 pass over h1, then retire
    {
      f32x4 z2a[2];
      { const f32x4 v = {c2v,c2v,c2v,c2v}; z2a[0]=v; z2a[1]=v; }
#pragma unroll
      for (int kt = 0; kt < 2; ++kt) {
        const bf16x8 b = glb_frag(fM2N, kt*4 + wave, lane);
#pragma unroll
        for (int rt = 0; rt < 2; ++rt) z2a[rt] = mfma16(h2f[kt][rt], b, z2a[rt]);
      }
#pragma unroll
      for (int kt = 0; kt < 4; ++kt) {
        const bf16x8 a0 = lds_frag(h1b + (0*16 + m)*136 + kt*32 + q*8);
        const bf16x8 a1 = lds_frag(h1b + (1*16 + m)*136 + kt*32 + q*8);
        const bf16x8 b  = glb_frag(fW2T, kt*4 + wave, lane);
        z2a[0] = mfma16(a0, b, z2a[0]);
        z2a[1] = mfma16(a1, b, z2a[1]);
      }
#pragma unroll
      for (int rt = 0; rt < 2; ++rt)
#pragma unroll
        for (int r = 0; r < 4; ++r) h2v[rt][r] += tanh_fast(z2a[rt][r]);
    }

    // ---- level 1: M1 pass (z1 = A1 - h1@M1), retire
    {
      f32x4 z1[2][2];
#pragma unroll
      for (int rt = 0; rt < 2; ++rt) { z1[rt][0] = A1[rt][0]; z1[rt][1] = A1[rt][1]; }
#pragma unroll
      for (int kt = 0; kt < 4; ++kt) {
        const bf16x8 a0 = lds_frag(h1b + (0*16 + m)*136 + kt*32 + q*8);
        const bf16x8 a1 = lds_frag(h1b + (1*16 + m)*136 + kt*32 + q*8);
        const bf16x8 b0 = glb_frag(fM1N, kt*8 + 2*wave + 0, lane);
        const bf16x8 b1 = glb_frag(fM1N, kt*8 + 2*wave + 1, lane);
        z1[0][0] = mfma16(a0, b0, z1[0][0]); z1[0][1] = mfma16(a0, b1, z1[0][1]);
        z1[1][0] = mfma16(a1, b0, z1[1][0]); z1[1][1] = mfma16(a1, b1, z1[1][1]);
      }
#pragma unroll
      for (int rt = 0; rt < 2; ++rt)
#pragma unroll
        for (int nt = 0; nt < 2; ++nt)
#pragma unroll
          for (int r = 0; r < 4; ++r) h1v[rt][nt][r] += tanh_fast(z1[rt][nt][r]);
    }

    // ---- level 1: U1 pass (z1 = h1@U1 + U1_b), retire
    {
      f32x4 z1[2][2];
      { const f32x4 v0 = {b1v0,b1v0,b1v0,b1v0};
        const f32x4 v1 = {b1v1,b1v1,b1v1,b1v1};
#pragma unroll
        for (int rt = 0; rt < 2; ++rt) { z1[rt][0] = v0; z1[rt][1] = v1; }
      }
#pragma unroll
      for (int kt = 0; kt < 4; ++kt) {
        const bf16x8 a0 = lds_frag(h1b + (0*16 + m)*136 + kt*32 + q*8);
        const bf16x8 a1 = lds_frag(h1b + (1*16 + m)*136 + kt*32 + q*8);
        const bf16x8 b0 = glb_frag(fU1T, kt*8 + 2*wave + 0, lane);
        const bf16x8 b1 = glb_frag(fU1T, kt*8 + 2*wave + 1, lane);
        z1[0][0] = mfma16(a0, b0, z1[0][0]); z1[0][1] = mfma16(a0, b1, z1[0][1]);
        z1[1][0] = mfma16(a1, b0, z1[1][0]); z1[1][1] = mfma16(a1, b1, z1[1][1]);
      }
#pragma unroll
      for (int rt = 0; rt < 2; ++rt)
#pragma unroll
        for (int nt = 0; nt < 2; ++nt)
#pragma unroll
          for (int r = 0; r < 4; ++r) h1v[rt][nt][r] += tanh_fast(z1[rt][nt][r]);
    }

    __syncthreads();   // everyone done reading old h
    // write back new h (bf16, C-layout: row = rt*16 + q*4 + r, cols owned by wave)
#pragma unroll
    for (int rt = 0; rt < 2; ++rt) {
#pragma unroll
      for (int nt = 0; nt < 2; ++nt)
#pragma unroll
        for (int r = 0; r < 4; ++r)
          h1b[(rt*16 + q*4 + r)*136 + (2*wave + nt)*16 + m] = f2bf(h1v[rt][nt][r]);
#pragma unroll
      for (int r = 0; r < 4; ++r)
        h2b[(rt*16 + q*4 + r)*72 + wave*16 + m] = f2bf(h2v[rt][r]);
    }
#pragma unroll
    for (int r = 0; r < 4; ++r)
      h3b[(rt3*16 + q*4 + r)*40 + nt3*16 + m] = f2bf(h3v[r]);
    __syncthreads();
  }

  // ---------------- epilogue: out = h3 @ clf^T + clf_b (waves 0,1 = row tiles)
  if (wave < 2) {
    f32x4 o;
    { const float cb = (m < 10) ? clf_b[m] : 0.f; o = (f32x4){cb, cb, cb, cb}; }
    const bf16x8 a = lds_frag(h3b + (wave*16 + m)*40 + q*8);
    const bf16x8 b = glb_frag(fCLF, 0, lane);
    o = mfma16(a, b, o);
    if (m < 10) {
#pragma unroll
      for (int r = 0; r < 4; ++r) {
        const int row = rowBase + wave*16 + q*4 + r;
        out[(size_t)row*10 + m] = o[r];
      }
    }
  }
}

// ============ launch ============
extern "C" void kernel_launch(void* const* d_in, const int* in_sizes, int n_in,
                              void* d_out, int out_size, void* d_ws, size_t ws_size,
                              hipStream_t stream)
{
  (void)in_sizes; (void)n_in; (void)out_size; (void)ws_size;
  const float* x     = (const float*)d_in[0];
  const float* W1_w  = (const float*)d_in[1];
  const float* W1_b  = (const float*)d_in[2];
  const float* U1_w  = (const float*)d_in[3];
  const float* U1_b  = (const float*)d_in[4];
  const float* W2_w  = (const float*)d_in[5];
  const float* W2_b  = (const float*)d_in[6];
  const float* U2_w  = (const float*)d_in[7];
  const float* U2_b  = (const float*)d_in[8];
  const float* W3_w  = (const float*)d_in[9];
  const float* W3_b  = (const float*)d_in[10];
  const float* U3_w  = (const float*)d_in[11];
  const float* U3_b  = (const float*)d_in[12];
  const float* fb3_w = (const float*)d_in[13];
  const float* fb3_b = (const float*)d_in[14];
  const float* fb2_w = (const float*)d_in[15];
  const float* fb2_b = (const float*)d_in[16];
  const float* fb1_w = (const float*)d_in[17];
  const float* fb1_b = (const float*)d_in[18];
  const float* clf_w = (const float*)d_in[19];
  const float* clf_b = (const float*)d_in[20];
  const int*   steps = (const int*)d_in[21];

  float* wsf = (float*)d_ws;
  unsigned short* frags = (unsigned short*)d_ws + 43520;

  hipLaunchKernelGGL(pcnet_prep_m1, dim3(128), dim3(128), 0, stream,
                     W1_w, fb1_w, wsf);
  hipLaunchKernelGGL(pcnet_prep_rest, dim3(1336), dim3(256), 0, stream,
                     W1_w, W1_b, W2_w, W2_b, W3_w, W3_b,
                     fb1_b, fb2_w, fb2_b, fb3_w, fb3_b, wsf);
  hipLaunchKernelGGL(pcnet_swz, dim3(77), dim3(256), 0, stream,
                     W1_w, U1_w, W2_w, U2_w, W3_w, U3_w, clf_w, wsf, frags);
  hipLaunchKernelGGL(pcnet_main, dim3(2048), dim3(256), 0, stream,
                     x, wsf + WSF_C, U1_b, U2_b, U3_b, clf_b, frags, steps,
                     (float*)d_out);
}